// Round 3
// baseline (126.071 us; speedup 1.0000x reference)
//
#include <hip/hip_runtime.h>
#include <hip/hip_bf16.h>

// Problem constants (from reference):
//   S=256 samples, T=1024, D=4, P=8, K=64 (K only shapes the blocked form;
//   the math reduces exactly to param[t] = z[t] + a[t-1]*param[t-1], a[-1]=0).
// Dtypes (deduced R1/R2): inputs are FLOAT32 storage (values bf16-rounded by
// harness, hence bf16-eps threshold); OUTPUTS ARE FLOAT32 (R2's 9.64 error ==
// max|log_prob| proved bf16 stores misplaced lp into the f32 param region).
#define T_DIM 1024
#define D_DIM 4
#define P_DIM 8
#define S_DIM 256
#define DP 32                 // D*P
#define TDP (T_DIM * DP)      // 32768 elements per sample
#define LOG2PI_F 1.8378770664093453f

// ---------------------------------------------------------------------------
// Kernel A: build per-(t,d,p) table: {mean, sv, nls, A}
//   A[t]   = sigmoid(a_raw[t-1, dim_idx[d]])  (A[0] = 0)
//   sv     = softplus(s_raw[t, dim_idx[d], p])
//   mean   = (1 - A[t]) * m[t, dim_idx[d], p]
//   nls    = -log(sv) - 0.5*log(2*pi)
// ---------------------------------------------------------------------------
__global__ __launch_bounds__(256) void build_tbl(
    const float* __restrict__ m,
    const float* __restrict__ s_raw,
    const float* __restrict__ a_raw,
    const int* __restrict__ dim_idx,
    float4* __restrict__ tbl)
{
    int idx = blockIdx.x * 256 + threadIdx.x;   // grid covers exactly TDP
    int t  = idx >> 5;
    int dp = idx & 31;
    int d  = dp >> 3;
    int p  = dp & 7;
    int di = dim_idx[d];

    float mm = m[(t * D_DIM + di) * P_DIM + p];
    float sr = s_raw[(t * D_DIM + di) * P_DIM + p];
    // softplus, numerically safe (values here ~ -6, but guard anyway)
    float sv = (sr > 20.0f) ? sr : log1pf(expf(sr));

    float A = 0.0f;
    if (t > 0) {
        float ar = a_raw[(t - 1) * D_DIM + di];
        A = 1.0f / (1.0f + expf(-ar));
    }
    float mean = (1.0f - A) * mm;
    float nls  = -logf(sv) - 0.5f * LOG2PI_F;

    tbl[idx] = make_float4(mean, sv, nls, A);
}

// ---------------------------------------------------------------------------
// Kernel B: 8192 independent AR(1) scans.
// One block per sample s. 256 threads = 8 time-chunks (cj) x 32 chains (dp).
// T tiled into 16 tiles of 64 t; per tile each thread scans 8 steps locally,
// carries combined serially across the 8 chunks in LDS (cj==0 half-wave),
// running carry across tiles held in cj==0 thread registers.
// Next tile's global loads are prefetched into registers before the barriers.
// ---------------------------------------------------------------------------
__global__ __launch_bounds__(256) void scan_kernel(
    const float* __restrict__ noise,
    const float4* __restrict__ tbl,
    float* __restrict__ param_out,
    float* __restrict__ lp_out)
{
    const int s   = blockIdx.x;
    const int tid = threadIdx.x;
    const int dp  = tid & 31;
    const int cj  = tid >> 5;          // chunk 0..7

    __shared__ float sh_pl[8][32];
    __shared__ float sh_m[8][32];
    __shared__ float sh_ci[8][32];

    const size_t sbase = (size_t)s * TDP;

    float carry = 0.0f;                // running param carry (valid on cj==0)

    // prologue: load tile 0
    float  na[8];
    float4 ca[8];
    {
        const int tb = (cj * 8) * DP + dp;
        #pragma unroll
        for (int k = 0; k < 8; ++k) {
            na[k] = noise[sbase + tb + k * DP];
            ca[k] = tbl[tb + k * DP];
        }
    }

    for (int tile = 0; tile < 16; ++tile) {
        // ---- prefetch next tile (wraps to 0 on last iter; harmless L2 hit)
        float  nb[8];
        float4 cb[8];
        {
            const int tn  = (tile + 1 < 16) ? tile + 1 : 0;
            const int tb2 = (tn * 64 + cj * 8) * DP + dp;
            #pragma unroll
            for (int k = 0; k < 8; ++k) {
                nb[k] = noise[sbase + tb2 + k * DP];
                cb[k] = tbl[tb2 + k * DP];
            }
        }

        const int tb = (tile * 64 + cj * 8) * DP + dp;

        // ---- local 8-step scan + log_prob store
        float pl[8], Mk[8];
        float rp = 0.0f, rm = 1.0f;
        #pragma unroll
        for (int k = 0; k < 8; ++k) {
            const float n = na[k];
            const float z = ca[k].x + ca[k].y * n;              // mean + sv*noise
            lp_out[sbase + tb + k * DP] = ca[k].z - 0.5f * n * n; // nls - 0.5*n^2
            rp = z + ca[k].w * rp;                              // local prefix
            rm = rm * ca[k].w;                                  // prod of A
            pl[k] = rp;
            Mk[k] = rm;
        }

        sh_pl[cj][dp] = rp;
        sh_m[cj][dp]  = rm;
        __syncthreads();

        // ---- serial carry combine across 8 chunks (one half-wave)
        if (cj == 0) {
            float cr = carry;
            #pragma unroll
            for (int cc = 0; cc < 8; ++cc) {
                sh_ci[cc][dp] = cr;                  // carry-in for chunk cc
                cr = sh_pl[cc][dp] + sh_m[cc][dp] * cr;
            }
            carry = cr;                               // carry into next tile
        }
        __syncthreads();

        // ---- fixup + param store
        const float ci = sh_ci[cj][dp];
        #pragma unroll
        for (int k = 0; k < 8; ++k) {
            param_out[sbase + tb + k * DP] = pl[k] + Mk[k] * ci;
        }

        // rotate prefetch buffers
        #pragma unroll
        for (int k = 0; k < 8; ++k) { na[k] = nb[k]; ca[k] = cb[k]; }
    }
}

// ---------------------------------------------------------------------------
extern "C" void kernel_launch(void* const* d_in, const int* in_sizes, int n_in,
                              void* d_out, int out_size, void* d_ws, size_t ws_size,
                              hipStream_t stream)
{
    // setup_inputs order:
    // 0:y(1,T,D) 1:age(N) 2:m(T,D,P) 3:s_raw(T,D,P) 4:a_raw(T-1,D,1)
    // 5:noise(S,T,D,P) 6:cond_sample(S,D,P) 7:dim_idx(D) 8:compute_log_prob
    const float* m      = (const float*)d_in[2];
    const float* s_raw  = (const float*)d_in[3];
    const float* a_raw  = (const float*)d_in[4];
    const float* noise  = (const float*)d_in[5];
    const int*   dimidx = (const int*)d_in[7];

    float4* tbl = (float4*)d_ws;                       // 32768 * 16 B = 512 KB

    float* param_out = (float*)d_out;
    float* lp_out    = param_out + (size_t)S_DIM * TDP;

    build_tbl<<<TDP / 256, 256, 0, stream>>>(m, s_raw, a_raw, dimidx, tbl);
    scan_kernel<<<S_DIM, 256, 0, stream>>>(noise, tbl, param_out, lp_out);
}